// Round 3
// baseline (19.474 us; speedup 1.0000x reference)
//
#include <hip/hip_runtime.h>

#define NB 255              // branches; heap node id == branch id for a perfect tree
#define DEPTH 8
#define F 32
#define XSTRIDE 36          // padded floats per LDS row (144 B, 16B-aligned)
#define ROWS_PER_WAVE 64
#define CHUNKS 2            // chunks per wave, register-double-buffered
#define WAVES 4             // waves per block
#define N_ROWS 524288

__global__ __launch_bounds__(256) void tree_traverse_pipelined(
    const float* __restrict__ x,
    const int*   __restrict__ feature,
    const float* __restrict__ threshold,
    const float* __restrict__ value,
    float*       __restrict__ out)
{
    // Per-wave x staging region + one shared packed node table.
    __shared__ float xs[WAVES][ROWS_PER_WAVE * XSTRIDE];
    __shared__ int2  s_node[256];   // {feature, bitcast(threshold)}

    const int tid  = threadIdx.x;
    const int lane = tid & 63;
    const int wid  = tid >> 6;

    // Every wave redundantly stages the same table values -> benign duplicate
    // writes, so each wave only depends on its OWN ds_writes (no barrier).
    #pragma unroll
    for (int k = 0; k < 4; ++k) {
        int e = lane + 64 * k;
        if (e < NB) s_node[e] = make_int2(feature[e], __float_as_int(threshold[e]));
    }

    const int       gwave = blockIdx.x * WAVES + wid;
    const long long row0  = (long long)gwave * (ROWS_PER_WAVE * CHUNKS);
    const float4*   xg    = reinterpret_cast<const float4*>(x + row0 * F);

    // ---- issue both chunks' global loads up front (16 dwordx4 in flight) ----
    float4 A[8], B[8];
    #pragma unroll
    for (int j = 0; j < 8; ++j) A[j] = xg[j * 64 + lane];           // chunk 0
    #pragma unroll
    for (int j = 0; j < 8; ++j) B[j] = xg[512 + j * 64 + lane];     // chunk 1

    float* myxs = xs[wid];
    const float* row_x = &myxs[lane * XSTRIDE];

    #pragma unroll
    for (int c = 0; c < CHUNKS; ++c) {
        // ---- LDS stage this chunk (compiler waits only this chunk's vmcnt) ----
        #pragma unroll
        for (int j = 0; j < 8; ++j) {
            float4 v = (c == 0) ? A[j] : B[j];
            int f4idx = j * 64 + lane;          // float4 index within chunk
            int row   = f4idx >> 3;             // 8 float4 per row
            int cc    = f4idx & 7;
            *reinterpret_cast<float4*>(&myxs[row * XSTRIDE + cc * 4]) = v;
        }

        // ---- traverse: 8 dependent {table read, x gather, step} (same-wave
        //      lgkmcnt ordering; cross-lane within wave is safe, no barrier) ----
        int node = 0;
        #pragma unroll
        for (int d = 0; d < DEPTH; ++d) {
            int2  nd = s_node[node];
            float t  = __int_as_float(nd.y);
            node = 2 * node + 1 + (row_x[nd.x] > t ? 1 : 0);
        }
        const int leaf = node - NB;

        // ---- leaf value gather (8 KB table, L1-resident) + coalesced store ----
        const float4* v4 = reinterpret_cast<const float4*>(value + (size_t)leaf * 8);
        float4 v0 = v4[0];
        float4 v1 = v4[1];
        float4* o = reinterpret_cast<float4*>(out + (row0 + c * ROWS_PER_WAVE + lane) * 8);
        o[0] = v0;
        o[1] = v1;
    }
}

extern "C" void kernel_launch(void* const* d_in, const int* in_sizes, int n_in,
                              void* d_out, int out_size, void* d_ws, size_t ws_size,
                              hipStream_t stream) {
    (void)in_sizes; (void)n_in; (void)d_ws; (void)ws_size; (void)out_size;
    const float* x         = (const float*)d_in[0];
    const int*   feature   = (const int*)d_in[1];
    const float* threshold = (const float*)d_in[2];
    // d_in[3] = cond, d_in[4] = cond_mask — not needed (heap traversal is exact)
    const float* value     = (const float*)d_in[5];
    float*       out       = (float*)d_out;

    dim3 grid(N_ROWS / (ROWS_PER_WAVE * CHUNKS * WAVES));   // 1024 blocks
    dim3 block(256);
    tree_traverse_pipelined<<<grid, block, 0, stream>>>(x, feature, threshold, value, out);
}